// Round 8
// baseline (335.063 us; speedup 1.0000x reference)
//
#include <hip/hip_runtime.h>

typedef __bf16 bf16;
typedef __attribute__((ext_vector_type(8))) __bf16 bf16x8;
typedef __attribute__((ext_vector_type(4))) float f32x4;

#define T 128
#define DIM 4096
#define NACT 11468
#define A_PAD 11520
#define BK1 128
#define NC1 (DIM / BK1)     // 32 chunks, phase 1
#define NCH 6
#define KCH (A_PAD / NCH)   // 1920
#define NC2 (KCH / 64)      // 30 chunks, phase 2

#define GLOAD16(src, dst)                                                          \
  __builtin_amdgcn_global_load_lds(                                                \
      (__attribute__((address_space(1))) const void*)(src),                        \
      (__attribute__((address_space(3))) void*)(dst), 16, 0, 0)

#define WAITCNT(n) asm volatile("s_waitcnt vmcnt(" #n ")" ::: "memory")
#define BAR() __builtin_amdgcn_s_barrier()

// ---------------- pre-kernel: x fp32 -> bf16 ----------------
__global__ __launch_bounds__(256) void k_cvt_x(const float* __restrict__ x,
                                               bf16* __restrict__ xb) {
  int i = (blockIdx.x * 256 + threadIdx.x) * 8;
  f32x4 a = *(const f32x4*)(x + i);
  f32x4 b = *(const f32x4*)(x + i + 4);
  bf16x8 o;
  o[0] = (bf16)a[0]; o[1] = (bf16)a[1]; o[2] = (bf16)a[2]; o[3] = (bf16)a[3];
  o[4] = (bf16)b[0]; o[5] = (bf16)b[1]; o[6] = (bf16)b[2]; o[7] = (bf16)b[3];
  *(bf16x8*)(xb + i) = o;
}

// ---------------- phase 1: g_e = silu(x w1^T) * (x w3^T) * ew_e ----------------
// Block: 512 threads = 8 waves (4 m-groups x 2 n-groups); wave = 32 t x 16 a.
// BN=32, BK=128. LDS: 3 buffers x 32KB (w1[32][512B] | w3[32][512B], XOR-swizzled
// via pre-swizzled global source). Depth-2 counted-vmcnt staging: S(c+1) spans two
// full COMP periods. One barrier per chunk. 1 block/CU, grid 720 (93.75% util).
// Queue order per half-iter: W12(retire S(c)) BAR XLOAD(c+1) STAGE(c+2) W16 COMP(c).
__global__ __launch_bounds__(512, 1) void k_phase1(
    const bf16* __restrict__ xb,
    const float* __restrict__ w1e0, const float* __restrict__ w3e0,
    const float* __restrict__ w1e1, const float* __restrict__ w3e1,
    const float* __restrict__ ew, const int* __restrict__ ids,
    bf16* __restrict__ gws) {
  __shared__ __attribute__((aligned(16))) char smem[3][32768];
  const int e = blockIdx.y;
  const float* __restrict__ w1 = e ? w1e1 : w1e0;
  const float* __restrict__ w3 = e ? w3e1 : w3e0;
  bf16* __restrict__ g = gws + (size_t)e * T * A_PAD;

  const int tid = threadIdx.x;
  const int wv = tid >> 6;
  const int lane = tid & 63;
  const int ln = lane & 15;
  const int kh = lane >> 4;
  const int wm = wv >> 1;       // t-group: rows wm*32..+31
  const int wn = wv & 1;        // a-group: cols wn*16..+15
  const int bx32 = blockIdx.x * 32;

  // Staging: 32 x 1KB instrs/chunk over 8 waves = 4/wave. Wave wv -> mat wv>>2,
  // instr i = (wv&3)*4 + j covers LDS rows 2i,2i+1 (lane>>5 picks row), 512B each.
  const char* wmat = (const char*)((wv >> 2) ? w3 : w1);
  const int mo = (wv >> 2) * 16384;
  const char* sb[4];
  int sdo[4];
#pragma unroll
  for (int j = 0; j < 4; ++j) {
    const int i = (wv & 3) * 4 + j;
    const int row = 2 * i + (lane >> 5);
    int grow = bx32 + row;
    grow = grow < NACT ? grow : NACT - 1;
    const int kb = ((lane & 31) * 16) ^ ((row & 7) << 4);  // pre-swizzled source
    sb[j] = wmat + (size_t)grow * (DIM * 4) + kb;
    sdo[j] = mo + i * 1024;
  }

  const bf16* __restrict__ px = xb + (size_t)(wm * 32 + ln) * DIM + kh * 8;
  const int rowbase = (wn * 16 + ln) * 512;
  const int swz = (ln & 7) << 4;

  f32x4 accu[2], accg[2];
  accu[0] = (f32x4){0,0,0,0}; accu[1] = (f32x4){0,0,0,0};
  accg[0] = (f32x4){0,0,0,0}; accg[1] = (f32x4){0,0,0,0};
  bf16x8 xfA[8], xfB[8];

  auto STAGE = [&](int c, int b) {
    const size_t koff = (size_t)c * 512;
#pragma unroll
    for (int j = 0; j < 4; ++j) GLOAD16(sb[j] + koff, &smem[b][0] + sdo[j]);
  };
  auto XLOAD = [&](bf16x8 (&xf)[8], int c) {
    const bf16* p = px + (size_t)c * BK1;
#pragma unroll
    for (int mf = 0; mf < 2; ++mf)
#pragma unroll
      for (int ks = 0; ks < 4; ++ks)
        xf[mf * 4 + ks] = *(const bf16x8*)(p + (size_t)mf * 16 * DIM + ks * 32);
  };
  auto COMP = [&](const bf16x8 (&xf)[8], int b) {
    const char* b1 = &smem[b][0] + rowbase;
    const char* b3 = b1 + 16384;
#pragma unroll
    for (int ks = 0; ks < 4; ++ks) {
      const int o0 = (ks * 128 + kh * 32) ^ swz;
      const int o1 = (ks * 128 + kh * 32 + 16) ^ swz;
      f32x4 u0 = *(const f32x4*)(b1 + o0);
      f32x4 u1 = *(const f32x4*)(b1 + o1);
      f32x4 v0 = *(const f32x4*)(b3 + o0);
      f32x4 v1 = *(const f32x4*)(b3 + o1);
      bf16x8 f1, f3;
      f1[0] = (bf16)u0[0]; f1[1] = (bf16)u0[1]; f1[2] = (bf16)u0[2]; f1[3] = (bf16)u0[3];
      f1[4] = (bf16)u1[0]; f1[5] = (bf16)u1[1]; f1[6] = (bf16)u1[2]; f1[7] = (bf16)u1[3];
      f3[0] = (bf16)v0[0]; f3[1] = (bf16)v0[1]; f3[2] = (bf16)v0[2]; f3[3] = (bf16)v0[3];
      f3[4] = (bf16)v1[0]; f3[5] = (bf16)v1[1]; f3[6] = (bf16)v1[2]; f3[7] = (bf16)v1[3];
#pragma unroll
      for (int mf = 0; mf < 2; ++mf) {
        accg[mf] = __builtin_amdgcn_mfma_f32_16x16x32_bf16(xf[mf * 4 + ks], f1, accg[mf], 0, 0, 0);
        accu[mf] = __builtin_amdgcn_mfma_f32_16x16x32_bf16(xf[mf * 4 + ks], f3, accu[mf], 0, 0, 0);
      }
    }
  };

  // prologue: queue = [S(0) 4, x(0) 8, S(1) 4]
  STAGE(0, 0);
  XLOAD(xfA, 0);
  STAGE(1, 1);

  int bc = 0;  // buffer of chunk c; (c+1)->bn1, (c+2)->bn2, (c+3)->bc
  for (int c = 0; c <= NC1 - 4; c += 2) {
    const int bn1 = bc == 2 ? 0 : bc + 1;
    const int bn2 = bn1 == 2 ? 0 : bn1 + 1;
    // even chunk c (x in A, buf bc)
    WAITCNT(12);            // retire S(c); keep [x(c) 8, S(c+1) 4]
    BAR();                  // S(c) visible; all COMP(c-1) done -> bn2 writable
    XLOAD(xfB, c + 1);      // [x(c), S(c+1), x(c+1)]
    STAGE(c + 2, bn2);      // [x(c), S(c+1), x(c+1), S(c+2)] = 24
    WAITCNT(16);            // retire x(c); keep [S(c+1), x(c+1), S(c+2)]
    COMP(xfA, bc);
    // odd chunk c+1 (x in B, buf bn1)
    WAITCNT(12);            // retire S(c+1); keep [x(c+1), S(c+2)]
    BAR();                  // all COMP(c) done -> buf bc writable
    XLOAD(xfA, c + 2);
    STAGE(c + 3, bc);       // (c+3)%3 == c%3
    WAITCNT(16);            // retire x(c+1); keep [S(c+2), x(c+2), S(c+3)]
    COMP(xfB, bn1);
    bc = bn2;
  }
  // epilogue: chunks 30 (buf 0), 31 (buf 1); entry queue [S(30) 4, x(30) 8, S(31) 4]
  WAITCNT(12);              // retire S(30)
  BAR();
  XLOAD(xfB, NC1 - 1);      // [x(30), S(31), x(31)] = 20
  WAITCNT(12);              // retire x(30)
  COMP(xfA, 0);
  WAITCNT(8);               // retire S(31)
  BAR();
  WAITCNT(0);
  COMP(xfB, 1);

  // routing weights (swap if incoming expert_ids[0] != 0)
  float e0 = ew[0], e1 = ew[1];
  if (ids[0] != 0) { float t = e0; e0 = e1; e1 = t; }
  const float sel = e ? e1 : e0;
  const int a = bx32 + wn * 16 + ln;
  const bool valid = a < NACT;

#pragma unroll
  for (int mf = 0; mf < 2; ++mf) {
#pragma unroll
    for (int j = 0; j < 4; ++j) {
      const int t = wm * 32 + mf * 16 + kh * 4 + j;  // C/D: row=(lane>>4)*4+j, col=lane&15
      float up = accu[mf][j];
      float gt = accg[mf][j];
      float sg = gt / (1.f + __expf(-gt));
      float val = valid ? sg * up * sel : 0.f;
      g[(size_t)t * A_PAD + a] = (bf16)val;
    }
  }
}

// ---------------- phase 2: out += sum_e g_e @ w2_e  (split-K, atomic fp32) ----------------
// Block: 128 t x 128 d. 4 waves, wave = M=32 t x N=128 d. Chunk = 64 k-rows,
// each w2 row visited in 512B contiguous spans. LDS: 2 x 32KB [64k][128d] f32.
// Counted-vmcnt: per wave per chunk 8 stage gload_lds + 4 g loads. (working; keep)
__global__ __launch_bounds__(256, 2) void k_phase2(
    const bf16* __restrict__ gws,
    const float* __restrict__ w2e0, const float* __restrict__ w2e1,
    float* __restrict__ out) {
  __shared__ __attribute__((aligned(16))) char smem[2][32768];
  const int e = blockIdx.y / NCH;
  const int kc = blockIdx.y % NCH;
  const float* __restrict__ w2 = e ? w2e1 : w2e0;
  const bf16* __restrict__ g = gws + (size_t)e * T * A_PAD;

  const int tid = threadIdx.x;
  const int wv = tid >> 6;
  const int lane = tid & 63;
  const int ln = lane & 15;
  const int kh = lane >> 4;
  const int bx128 = blockIdx.x * 128;
  const int kcbase = kc * KCH;

  const bf16* __restrict__ pg = g + (size_t)(wv * 32 + ln) * A_PAD + kh * 8 + kcbase;

  f32x4 acc[2][8];
#pragma unroll
  for (int m = 0; m < 2; ++m)
#pragma unroll
    for (int n = 0; n < 8; ++n) acc[m][n] = (f32x4){0, 0, 0, 0};
  bf16x8 gf[2][2];

  auto STAGE2 = [&](int c, int b) {
    char* db = &smem[b][0] + (size_t)wv * 8192;
    const int kb = kcbase + c * 64;
#pragma unroll
    for (int i = 0; i < 8; ++i) {
      int kr = kb + (wv * 8 + i) * 2 + (lane >> 5);
      kr = kr < NACT ? kr : NACT - 1;  // dup row x g==0 pad -> 0 contribution
      const char* src = (const char*)w2 + ((size_t)kr * DIM + bx128) * 4 + (lane & 31) * 16;
      GLOAD16(src, db + i * 1024);
    }
  };
  auto GLOADG = [&](int c) {
    const bf16* p = pg + (size_t)c * 64;
#pragma unroll
    for (int m = 0; m < 2; ++m)
#pragma unroll
      for (int ks = 0; ks < 2; ++ks)
        gf[m][ks] = *(const bf16x8*)(p + (size_t)m * 16 * A_PAD + ks * 32);
  };
  auto COMP2 = [&](int b) {
    const char* base = &smem[b][0];
#pragma unroll
    for (int ks = 0; ks < 2; ++ks)
#pragma unroll
      for (int n = 0; n < 8; ++n) {
        bf16x8 wf;
#pragma unroll
        for (int j = 0; j < 8; ++j) {
          float f = *(const float*)(base + (ks * 32 + kh * 8 + j) * 512 + (n * 16 + ln) * 4);
          wf[j] = (bf16)f;
        }
#pragma unroll
        for (int m = 0; m < 2; ++m)
          acc[m][n] = __builtin_amdgcn_mfma_f32_16x16x32_bf16(gf[m][ks], wf, acc[m][n], 0, 0, 0);
      }
  };

  STAGE2(0, 0);
  for (int c = 0; c < NC2; ++c) {
    const int b = c & 1;
    GLOADG(c);         // outstanding: S(c)8 + g4
    WAITCNT(4);        // retire S(c); keep g
    BAR();
    if (c + 1 < NC2) {
      STAGE2(c + 1, b ^ 1);  // outstanding: g4 + S(c+1)8
      WAITCNT(8);            // retire g(c); keep S(c+1)
    } else {
      WAITCNT(0);
    }
    COMP2(b);
  }

  const int dbase = bx128 + ln;
#pragma unroll
  for (int m = 0; m < 2; ++m) {
#pragma unroll
    for (int n = 0; n < 8; ++n) {
#pragma unroll
      for (int j = 0; j < 4; ++j) {
        const int t = wv * 32 + m * 16 + kh * 4 + j;
        atomicAdd(out + (size_t)t * DIM + dbase + n * 16, acc[m][n][j]);
      }
    }
  }
}

// ---------------- launch ----------------
extern "C" void kernel_launch(void* const* d_in, const int* in_sizes, int n_in,
                              void* d_out, int out_size, void* d_ws, size_t ws_size,
                              hipStream_t stream) {
  const float* x    = (const float*)d_in[0];
  const float* ew   = (const float*)d_in[1];
  const int*   ids  = (const int*)d_in[2];
  const float* w1e0 = (const float*)d_in[3];
  const float* w3e0 = (const float*)d_in[4];
  const float* w2e0 = (const float*)d_in[5];
  const float* w1e1 = (const float*)d_in[6];
  const float* w3e1 = (const float*)d_in[7];
  const float* w2e1 = (const float*)d_in[8];
  float* out = (float*)d_out;

  bf16* xb = (bf16*)d_ws;                                   // 128*4096*2 = 1 MB
  bf16* g  = (bf16*)((char*)d_ws + (size_t)T * DIM * 2);    // 2 * 128*11520*2 = 5.9 MB

  hipMemsetAsync(d_out, 0, (size_t)T * DIM * sizeof(float), stream);
  k_cvt_x<<<dim3((T * DIM) / (256 * 8)), 256, 0, stream>>>(x, xb);
  k_phase1<<<dim3(A_PAD / 32, 2), 512, 0, stream>>>(xb, w1e0, w3e0, w1e1, w3e1, ew, ids, g);
  k_phase2<<<dim3(DIM / 128, 2 * NCH), 256, 0, stream>>>(g, w2e0, w2e1, out);
}

// Round 9
// 289.575 us; speedup vs baseline: 1.1571x; 1.1571x over previous
//
#include <hip/hip_runtime.h>

typedef __bf16 bf16;
typedef __attribute__((ext_vector_type(8))) __bf16 bf16x8;
typedef __attribute__((ext_vector_type(4))) __bf16 bf16x4;
typedef __attribute__((ext_vector_type(4))) float f32x4;

#define T 128
#define DIM 4096
#define NACT 11468
#define A_PAD 11520
#define BK1 128
#define NC1 (DIM / BK1)     // 32 chunks, phase 1
#define NCH 6
#define KCH (A_PAD / NCH)   // 1920
#define NC2 (KCH / 64)      // 30 chunks, phase 2

#define GLOAD16(src, dst)                                                          \
  __builtin_amdgcn_global_load_lds(                                                \
      (__attribute__((address_space(1))) const void*)(src),                        \
      (__attribute__((address_space(3))) void*)(dst), 16, 0, 0)

#define WAITCNT(n) asm volatile("s_waitcnt vmcnt(" #n ")" ::: "memory")
#define BAR() __builtin_amdgcn_s_barrier()

// ---------------- pre-kernel: x fp32 -> bf16, XOR-swizzled rows ----------------
// xb[t] is an 8192B row; within each 256B span, 16B block at kb is stored at
// kb ^ ((t&7)<<4). Stage sources stay linear; LDS reads use the same XOR.
__global__ __launch_bounds__(256) void k_cvt_x(const float* __restrict__ x,
                                               bf16* __restrict__ xb) {
  int idx = blockIdx.x * 256 + threadIdx.x;   // 16B output group
  int i = idx * 8;
  f32x4 a = *(const f32x4*)(x + i);
  f32x4 b = *(const f32x4*)(x + i + 4);
  bf16x8 o;
  o[0] = (bf16)a[0]; o[1] = (bf16)a[1]; o[2] = (bf16)a[2]; o[3] = (bf16)a[3];
  o[4] = (bf16)b[0]; o[5] = (bf16)b[1]; o[6] = (bf16)b[2]; o[7] = (bf16)b[3];
  const int t = idx >> 9;           // 512 groups per 8192B row
  const int kb = (idx & 511) * 16;  // byte offset in row
  const int ob = t * 8192 + (kb & ~255) + ((kb & 255) ^ ((t & 7) << 4));
  *(bf16x8*)((char*)xb + ob) = o;
}

// ---------------- phase 1: g_e = silu(x w1^T) * (x w3^T) * ew_e ----------------
// Operand-swapped GEMM: weights = A (registers, per-lane row loads), x = B (LDS).
// Block: 256 t = 4 waves; wave = 16 a-rows (M) x all 128 t (N, nf=0..7).
// BN=64 a-rows/block -> grid (180,2): x read once per block (no duplication).
// LDS: 2 x 32KB x-chunk [128t][256B], swizzled. Weights: half-chunk (ks pair)
// prefetch with counted vmcnt; queue invariant [Wh0 8, Wh1 8, S 8] = 24.
__global__ __launch_bounds__(256, 2) void k_phase1(
    const bf16* __restrict__ xb,
    const float* __restrict__ w1e0, const float* __restrict__ w3e0,
    const float* __restrict__ w1e1, const float* __restrict__ w3e1,
    const float* __restrict__ ew, const int* __restrict__ ids,
    bf16* __restrict__ gws) {
  __shared__ __attribute__((aligned(16))) char smem[2][32768];
  const int e = blockIdx.y;
  const float* __restrict__ w1 = e ? w1e1 : w1e0;
  const float* __restrict__ w3 = e ? w3e1 : w3e0;
  bf16* __restrict__ g = gws + (size_t)e * T * A_PAD;

  const int tid = threadIdx.x;
  const int wv = tid >> 6;
  const int lane = tid & 63;
  const int ln = lane & 15;
  const int kh = lane >> 4;
  const int bx64 = blockIdx.x * 64;

  // per-lane weight row (A-frag row = lane&15), k-offset kh*8 f32 = 32B
  const int arow = bx64 + wv * 16 + ln;
  const int arow_c = arow < NACT ? arow : NACT - 1;
  const char* pa[2];
  pa[0] = (const char*)w1 + (size_t)arow_c * 16384 + kh * 32;
  pa[1] = (const char*)w3 + (size_t)arow_c * 16384 + kh * 32;

  // x staging: 8 gload_lds per wave per chunk; instr j covers t-rows wv*32+j*4..+3
  const char* sx[8];
#pragma unroll
  for (int j = 0; j < 8; ++j) {
    const int t0 = wv * 32 + j * 4 + (lane >> 4);
    sx[j] = (const char*)xb + (size_t)t0 * 8192 + (lane & 15) * 16;
  }

  const int lnoff = ln * 256;
  const int swz = (ln & 7) << 4;

  f32x4 accg[8], accu[8];
#pragma unroll
  for (int n = 0; n < 8; ++n) {
    accg[n] = (f32x4){0, 0, 0, 0};
    accu[n] = (f32x4){0, 0, 0, 0};
  }

  f32x4 r0[2][2][2], r1[2][2][2];  // raw f32 weights, half 0 (ks 0,1) / half 1 (ks 2,3)
  bf16x8 wf[2][4];                 // converted frags [mat][ks]

#define WLOADH(RAW, C, H)                                                        \
  do {                                                                           \
    _Pragma("unroll") for (int m = 0; m < 2; ++m)                                \
        _Pragma("unroll") for (int k2 = 0; k2 < 2; ++k2) {                       \
      const size_t off = (size_t)(C) * 512 + ((H) * 2 + k2) * 128;               \
      RAW[m][k2][0] = *(const f32x4*)(pa[m] + off);                              \
      RAW[m][k2][1] = *(const f32x4*)(pa[m] + off + 16);                         \
    }                                                                            \
  } while (0)

#define CVTH(RAW, H)                                                             \
  do {                                                                           \
    _Pragma("unroll") for (int m = 0; m < 2; ++m)                                \
        _Pragma("unroll") for (int k2 = 0; k2 < 2; ++k2) {                       \
      bf16x8 f;                                                                  \
      f[0] = (bf16)RAW[m][k2][0][0]; f[1] = (bf16)RAW[m][k2][0][1];              \
      f[2] = (bf16)RAW[m][k2][0][2]; f[3] = (bf16)RAW[m][k2][0][3];              \
      f[4] = (bf16)RAW[m][k2][1][0]; f[5] = (bf16)RAW[m][k2][1][1];              \
      f[6] = (bf16)RAW[m][k2][1][2]; f[7] = (bf16)RAW[m][k2][1][3];              \
      wf[m][(H) * 2 + k2] = f;                                                   \
    }                                                                            \
  } while (0)

  auto STAGE = [&](int c, int b) {
    const size_t koff = (size_t)c * 256;
#pragma unroll
    for (int j = 0; j < 8; ++j)
      GLOAD16(sx[j] + koff, &smem[b][0] + (wv * 8 + j) * 1024);
  };
  auto COMP = [&](int b) {
    const char* base = &smem[b][0] + lnoff;
#pragma unroll
    for (int ks = 0; ks < 4; ++ks) {
      const int ko = (ks * 64 + kh * 16) ^ swz;
#pragma unroll
      for (int n = 0; n < 8; ++n) {
        bf16x8 xf = *(const bf16x8*)(base + n * 4096 + ko);
        accg[n] = __builtin_amdgcn_mfma_f32_16x16x32_bf16(wf[0][ks], xf, accg[n], 0, 0, 0);
        accu[n] = __builtin_amdgcn_mfma_f32_16x16x32_bf16(wf[1][ks], xf, accu[n], 0, 0, 0);
      }
    }
  };

  // prologue: queue = [Wh0(0) 8, Wh1(0) 8, S(0) 8] = 24
  WLOADH(r0, 0, 0);
  WLOADH(r1, 0, 1);
  STAGE(0, 0);

  for (int c = 0; c < NC1; ++c) {
    const int b = c & 1;
    if (c + 1 < NC1) {
      WAITCNT(16);            // retire Wh0(c); keep [Wh1(c), S(c)]
      CVTH(r0, 0);
      WLOADH(r0, c + 1, 0);   // [Wh1(c), S(c), Wh0'] = 24
      WAITCNT(16);            // retire Wh1(c)
      CVTH(r1, 1);
      WLOADH(r1, c + 1, 1);   // [S(c), Wh0', Wh1'] = 24
      WAITCNT(16);            // retire S(c); keep [Wh0', Wh1'] in flight
      BAR();                  // x(c) visible; all COMP(c-1) done
      STAGE(c + 1, b ^ 1);    // [Wh0', Wh1', S'] = 24
      COMP(b);
    } else {
      WAITCNT(16);            // retire Wh0(c)
      CVTH(r0, 0);
      WAITCNT(8);             // retire Wh1(c)
      CVTH(r1, 1);
      WAITCNT(0);             // retire S(c)
      BAR();
      COMP(b);
    }
  }

  // routing weights (swap if incoming expert_ids[0] != 0)
  float e0 = ew[0], e1 = ew[1];
  if (ids[0] != 0) { float t = e0; e0 = e1; e1 = t; }
  const float sel = e ? e1 : e0;
  const int a0 = bx64 + wv * 16 + kh * 4;  // C/D: row(a) = (lane>>4)*4+j, col(t) = lane&15
  const bool valid = a0 < NACT;            // NACT%4==0 -> quad all-or-none

#pragma unroll
  for (int n = 0; n < 8; ++n) {
    const int t = n * 16 + ln;
    bf16x4 q;
#pragma unroll
    for (int j = 0; j < 4; ++j) {
      float gt = accg[n][j];
      float up = accu[n][j];
      float sg = gt / (1.f + __expf(-gt));
      float val = valid ? sg * up * sel : 0.f;  // zero pad region: phase 2 needs it
      q[j] = (bf16)val;
    }
    *(bf16x4*)(g + (size_t)t * A_PAD + a0) = q;
  }
#undef WLOADH
#undef CVTH
}

// ---------------- phase 2: out += sum_e g_e @ w2_e  (split-K, atomic fp32) ----------------
// Block: 128 t x 128 d. 4 waves, wave = M=32 t x N=128 d. Chunk = 64 k-rows,
// each w2 row visited in 512B contiguous spans. LDS: 2 x 32KB [64k][128d] f32.
// Counted-vmcnt: per wave per chunk 8 stage gload_lds + 4 g loads. (working; keep)
__global__ __launch_bounds__(256, 2) void k_phase2(
    const bf16* __restrict__ gws,
    const float* __restrict__ w2e0, const float* __restrict__ w2e1,
    float* __restrict__ out) {
  __shared__ __attribute__((aligned(16))) char smem[2][32768];
  const int e = blockIdx.y / NCH;
  const int kc = blockIdx.y % NCH;
  const float* __restrict__ w2 = e ? w2e1 : w2e0;
  const bf16* __restrict__ g = gws + (size_t)e * T * A_PAD;

  const int tid = threadIdx.x;
  const int wv = tid >> 6;
  const int lane = tid & 63;
  const int ln = lane & 15;
  const int kh = lane >> 4;
  const int bx128 = blockIdx.x * 128;
  const int kcbase = kc * KCH;

  const bf16* __restrict__ pg = g + (size_t)(wv * 32 + ln) * A_PAD + kh * 8 + kcbase;

  f32x4 acc[2][8];
#pragma unroll
  for (int m = 0; m < 2; ++m)
#pragma unroll
    for (int n = 0; n < 8; ++n) acc[m][n] = (f32x4){0, 0, 0, 0};
  bf16x8 gf[2][2];

  auto STAGE2 = [&](int c, int b) {
    char* db = &smem[b][0] + (size_t)wv * 8192;
    const int kb = kcbase + c * 64;
#pragma unroll
    for (int i = 0; i < 8; ++i) {
      int kr = kb + (wv * 8 + i) * 2 + (lane >> 5);
      kr = kr < NACT ? kr : NACT - 1;  // dup row x g==0 pad -> 0 contribution
      const char* src = (const char*)w2 + ((size_t)kr * DIM + bx128) * 4 + (lane & 31) * 16;
      GLOAD16(src, db + i * 1024);
    }
  };
  auto GLOADG = [&](int c) {
    const bf16* p = pg + (size_t)c * 64;
#pragma unroll
    for (int m = 0; m < 2; ++m)
#pragma unroll
      for (int ks = 0; ks < 2; ++ks)
        gf[m][ks] = *(const bf16x8*)(p + (size_t)m * 16 * A_PAD + ks * 32);
  };
  auto COMP2 = [&](int b) {
    const char* base = &smem[b][0];
#pragma unroll
    for (int ks = 0; ks < 2; ++ks)
#pragma unroll
      for (int n = 0; n < 8; ++n) {
        bf16x8 wf;
#pragma unroll
        for (int j = 0; j < 8; ++j) {
          float f = *(const float*)(base + (ks * 32 + kh * 8 + j) * 512 + (n * 16 + ln) * 4);
          wf[j] = (bf16)f;
        }
#pragma unroll
        for (int m = 0; m < 2; ++m)
          acc[m][n] = __builtin_amdgcn_mfma_f32_16x16x32_bf16(gf[m][ks], wf, acc[m][n], 0, 0, 0);
      }
  };

  STAGE2(0, 0);
  for (int c = 0; c < NC2; ++c) {
    const int b = c & 1;
    GLOADG(c);         // outstanding: S(c)8 + g4
    WAITCNT(4);        // retire S(c); keep g
    BAR();
    if (c + 1 < NC2) {
      STAGE2(c + 1, b ^ 1);  // outstanding: g4 + S(c+1)8
      WAITCNT(8);            // retire g(c); keep S(c+1)
    } else {
      WAITCNT(0);
    }
    COMP2(b);
  }

  const int dbase = bx128 + ln;
#pragma unroll
  for (int m = 0; m < 2; ++m) {
#pragma unroll
    for (int n = 0; n < 8; ++n) {
#pragma unroll
      for (int j = 0; j < 4; ++j) {
        const int t = wv * 32 + m * 16 + kh * 4 + j;
        atomicAdd(out + (size_t)t * DIM + dbase + n * 16, acc[m][n][j]);
      }
    }
  }
}

// ---------------- launch ----------------
extern "C" void kernel_launch(void* const* d_in, const int* in_sizes, int n_in,
                              void* d_out, int out_size, void* d_ws, size_t ws_size,
                              hipStream_t stream) {
  const float* x    = (const float*)d_in[0];
  const float* ew   = (const float*)d_in[1];
  const int*   ids  = (const int*)d_in[2];
  const float* w1e0 = (const float*)d_in[3];
  const float* w3e0 = (const float*)d_in[4];
  const float* w2e0 = (const float*)d_in[5];
  const float* w1e1 = (const float*)d_in[6];
  const float* w3e1 = (const float*)d_in[7];
  const float* w2e1 = (const float*)d_in[8];
  float* out = (float*)d_out;

  bf16* xb = (bf16*)d_ws;                                   // 128*4096*2 = 1 MB (swizzled)
  bf16* g  = (bf16*)((char*)d_ws + (size_t)T * DIM * 2);    // 2 * 128*11520*2 = 5.9 MB

  hipMemsetAsync(d_out, 0, (size_t)T * DIM * sizeof(float), stream);
  k_cvt_x<<<dim3((T * DIM) / (256 * 8)), 256, 0, stream>>>(x, xb);
  k_phase1<<<dim3(A_PAD / 64, 2), 256, 0, stream>>>(xb, w1e0, w3e0, w1e1, w3e1, ew, ids, g);
  k_phase2<<<dim3(DIM / 128, 2 * NCH), 256, 0, stream>>>(g, w2e0, w2e1, out);
}

// Round 10
// 274.757 us; speedup vs baseline: 1.2195x; 1.0539x over previous
//
#include <hip/hip_runtime.h>

typedef __bf16 bf16;
typedef __attribute__((ext_vector_type(8))) __bf16 bf16x8;
typedef __attribute__((ext_vector_type(4))) __bf16 bf16x4;
typedef __attribute__((ext_vector_type(4))) float f32x4;

#define T 128
#define DIM 4096
#define NACT 11468
#define A_PAD 11520
#define BK1 128
#define NC1 (DIM / BK1)     // 32 chunks, phase 1 (power of 2)
#define NCH 6
#define KCH (A_PAD / NCH)   // 1920
#define NC2 (KCH / 64)      // 30 chunks, phase 2

#define GLOAD16(src, dst)                                                          \
  __builtin_amdgcn_global_load_lds(                                                \
      (__attribute__((address_space(1))) const void*)(src),                        \
      (__attribute__((address_space(3))) void*)(dst), 16, 0, 0)

#define WAITCNT(n) asm volatile("s_waitcnt vmcnt(" #n ")" ::: "memory")
#define BAR() __builtin_amdgcn_s_barrier()

// ---------------- pre-kernel: x fp32 -> bf16, XOR-swizzled rows ----------------
// xb[t] is an 8192B row; within each 256B span, 16B block at kb is stored at
// kb ^ ((t&7)<<4). Stage sources stay linear; LDS reads use the same XOR.
__global__ __launch_bounds__(256) void k_cvt_x(const float* __restrict__ x,
                                               bf16* __restrict__ xb) {
  int idx = blockIdx.x * 256 + threadIdx.x;   // 16B output group
  int i = idx * 8;
  f32x4 a = *(const f32x4*)(x + i);
  f32x4 b = *(const f32x4*)(x + i + 4);
  bf16x8 o;
  o[0] = (bf16)a[0]; o[1] = (bf16)a[1]; o[2] = (bf16)a[2]; o[3] = (bf16)a[3];
  o[4] = (bf16)b[0]; o[5] = (bf16)b[1]; o[6] = (bf16)b[2]; o[7] = (bf16)b[3];
  const int t = idx >> 9;           // 512 groups per 8192B row
  const int kb = (idx & 511) * 16;  // byte offset in row
  const int ob = t * 8192 + (kb & ~255) + ((kb & 255) ^ ((t & 7) << 4));
  *(bf16x8*)((char*)xb + ob) = o;
}

// ---------------- phase 1: g_e = silu(x w1^T) * (x w3^T) * ew_e ----------------
// Operand-swapped GEMM: weights = A (registers, per-lane row loads), x = B (LDS).
// Block: 256 t = 4 waves; wave = 16 a-rows (M) x all 128 t (N, nf=0..7).
// BN=64 a-rows/block -> grid (180,2). NEW (r10): per-block k-phase rotation
// koff = (7*bx+3*e)&31 so concurrent blocks hit all HBM channel-interleave
// phases instead of sweeping k in lockstep (the ~1.5 TB/s pin of rounds 4-9).
__global__ __launch_bounds__(256, 2) void k_phase1(
    const bf16* __restrict__ xb,
    const float* __restrict__ w1e0, const float* __restrict__ w3e0,
    const float* __restrict__ w1e1, const float* __restrict__ w3e1,
    const float* __restrict__ ew, const int* __restrict__ ids,
    bf16* __restrict__ gws) {
  __shared__ __attribute__((aligned(16))) char smem[2][32768];
  const int e = blockIdx.y;
  const float* __restrict__ w1 = e ? w1e1 : w1e0;
  const float* __restrict__ w3 = e ? w3e1 : w3e0;
  bf16* __restrict__ g = gws + (size_t)e * T * A_PAD;

  const int tid = threadIdx.x;
  const int wv = tid >> 6;
  const int lane = tid & 63;
  const int ln = lane & 15;
  const int kh = lane >> 4;
  const int bx64 = blockIdx.x * 64;
  const int koff = (blockIdx.x * 7 + e * 3) & (NC1 - 1);  // k-phase rotation

  // per-lane weight row (A-frag row = lane&15), k-offset kh*8 f32 = 32B
  const int arow = bx64 + wv * 16 + ln;
  const int arow_c = arow < NACT ? arow : NACT - 1;
  const char* pa[2];
  pa[0] = (const char*)w1 + (size_t)arow_c * 16384 + kh * 32;
  pa[1] = (const char*)w3 + (size_t)arow_c * 16384 + kh * 32;

  // x staging: 8 gload_lds per wave per chunk; instr j covers t-rows wv*32+j*4..+3
  const char* sx[8];
#pragma unroll
  for (int j = 0; j < 8; ++j) {
    const int t0 = wv * 32 + j * 4 + (lane >> 4);
    sx[j] = (const char*)xb + (size_t)t0 * 8192 + (lane & 15) * 16;
  }

  const int lnoff = ln * 256;
  const int swz = (ln & 7) << 4;

  f32x4 accg[8], accu[8];
#pragma unroll
  for (int n = 0; n < 8; ++n) {
    accg[n] = (f32x4){0, 0, 0, 0};
    accu[n] = (f32x4){0, 0, 0, 0};
  }

  f32x4 r0[2][2][2], r1[2][2][2];  // raw f32 weights, half 0 (ks 0,1) / half 1 (ks 2,3)
  bf16x8 wf[2][4];                 // converted frags [mat][ks]

#define WLOADH(RAW, C, H)                                                        \
  do {                                                                           \
    _Pragma("unroll") for (int m = 0; m < 2; ++m)                                \
        _Pragma("unroll") for (int k2 = 0; k2 < 2; ++k2) {                       \
      const size_t off = (size_t)(C) * 512 + ((H) * 2 + k2) * 128;               \
      RAW[m][k2][0] = *(const f32x4*)(pa[m] + off);                              \
      RAW[m][k2][1] = *(const f32x4*)(pa[m] + off + 16);                         \
    }                                                                            \
  } while (0)

#define CVTH(RAW, H)                                                             \
  do {                                                                           \
    _Pragma("unroll") for (int m = 0; m < 2; ++m)                                \
        _Pragma("unroll") for (int k2 = 0; k2 < 2; ++k2) {                       \
      bf16x8 f;                                                                  \
      f[0] = (bf16)RAW[m][k2][0][0]; f[1] = (bf16)RAW[m][k2][0][1];              \
      f[2] = (bf16)RAW[m][k2][0][2]; f[3] = (bf16)RAW[m][k2][0][3];              \
      f[4] = (bf16)RAW[m][k2][1][0]; f[5] = (bf16)RAW[m][k2][1][1];              \
      f[6] = (bf16)RAW[m][k2][1][2]; f[7] = (bf16)RAW[m][k2][1][3];              \
      wf[m][(H) * 2 + k2] = f;                                                   \
    }                                                                            \
  } while (0)

  auto STAGE = [&](int c, int b) {
    const size_t koff_b = (size_t)c * 256;
#pragma unroll
    for (int j = 0; j < 8; ++j)
      GLOAD16(sx[j] + koff_b, &smem[b][0] + (wv * 8 + j) * 1024);
  };
  auto COMP = [&](int b) {
    const char* base = &smem[b][0] + lnoff;
#pragma unroll
    for (int ks = 0; ks < 4; ++ks) {
      const int ko = (ks * 64 + kh * 16) ^ swz;
#pragma unroll
      for (int n = 0; n < 8; ++n) {
        bf16x8 xf = *(const bf16x8*)(base + n * 4096 + ko);
        accg[n] = __builtin_amdgcn_mfma_f32_16x16x32_bf16(wf[0][ks], xf, accg[n], 0, 0, 0);
        accu[n] = __builtin_amdgcn_mfma_f32_16x16x32_bf16(wf[1][ks], xf, accu[n], 0, 0, 0);
      }
    }
  };

  // prologue: queue = [Wh0 8, Wh1 8, S 8] = 24, all at chunk koff
  WLOADH(r0, koff, 0);
  WLOADH(r1, koff, 1);
  STAGE(koff, 0);

  for (int s = 0; s < NC1; ++s) {
    const int b = s & 1;
    const int cn = (s + 1 + koff) & (NC1 - 1);  // next chunk (wrapped)
    if (s + 1 < NC1) {
      WAITCNT(16);            // retire Wh0(s); keep [Wh1(s), S(s)]
      CVTH(r0, 0);
      WLOADH(r0, cn, 0);      // [Wh1(s), S(s), Wh0'] = 24
      WAITCNT(16);            // retire Wh1(s)
      CVTH(r1, 1);
      WLOADH(r1, cn, 1);      // [S(s), Wh0', Wh1'] = 24
      WAITCNT(16);            // retire S(s); keep [Wh0', Wh1'] in flight
      BAR();                  // x(s) visible; all COMP(s-1) done
      STAGE(cn, b ^ 1);       // [Wh0', Wh1', S'] = 24
      COMP(b);
    } else {
      WAITCNT(16);            // retire Wh0(s)
      CVTH(r0, 0);
      WAITCNT(8);             // retire Wh1(s)
      CVTH(r1, 1);
      WAITCNT(0);             // retire S(s)
      BAR();
      COMP(b);
    }
  }

  // routing weights (swap if incoming expert_ids[0] != 0)
  float e0 = ew[0], e1 = ew[1];
  if (ids[0] != 0) { float t = e0; e0 = e1; e1 = t; }
  const float sel = e ? e1 : e0;
  const int a0 = bx64 + wv * 16 + kh * 4;  // C/D: row(a) = (lane>>4)*4+j, col(t) = lane&15
  const bool valid = a0 < NACT;            // NACT%4==0 -> quad all-or-none

#pragma unroll
  for (int n = 0; n < 8; ++n) {
    const int t = n * 16 + ln;
    bf16x4 q;
#pragma unroll
    for (int j = 0; j < 4; ++j) {
      float gt = accg[n][j];
      float up = accu[n][j];
      float sg = gt / (1.f + __expf(-gt));
      float val = valid ? sg * up * sel : 0.f;  // zero pad region: phase 2 needs it
      q[j] = (bf16)val;
    }
    *(bf16x4*)(g + (size_t)t * A_PAD + a0) = q;
  }
#undef WLOADH
#undef CVTH
}

// ---------------- phase 2: out += sum_e g_e @ w2_e  (split-K, atomic fp32) ----------------
// Block: 128 t x 128 d. 4 waves, wave = M=32 t x N=128 d. Chunk = 64 k-rows,
// each w2 row visited in 512B contiguous spans. LDS: 2 x 32KB [64k][128d] f32.
// Counted-vmcnt: per wave per chunk 8 stage gload_lds + 4 g loads. (working; keep)
__global__ __launch_bounds__(256, 2) void k_phase2(
    const bf16* __restrict__ gws,
    const float* __restrict__ w2e0, const float* __restrict__ w2e1,
    float* __restrict__ out) {
  __shared__ __attribute__((aligned(16))) char smem[2][32768];
  const int e = blockIdx.y / NCH;
  const int kc = blockIdx.y % NCH;
  const float* __restrict__ w2 = e ? w2e1 : w2e0;
  const bf16* __restrict__ g = gws + (size_t)e * T * A_PAD;

  const int tid = threadIdx.x;
  const int wv = tid >> 6;
  const int lane = tid & 63;
  const int ln = lane & 15;
  const int kh = lane >> 4;
  const int bx128 = blockIdx.x * 128;
  const int kcbase = kc * KCH;

  const bf16* __restrict__ pg = g + (size_t)(wv * 32 + ln) * A_PAD + kh * 8 + kcbase;

  f32x4 acc[2][8];
#pragma unroll
  for (int m = 0; m < 2; ++m)
#pragma unroll
    for (int n = 0; n < 8; ++n) acc[m][n] = (f32x4){0, 0, 0, 0};
  bf16x8 gf[2][2];

  auto STAGE2 = [&](int c, int b) {
    char* db = &smem[b][0] + (size_t)wv * 8192;
    const int kb = kcbase + c * 64;
#pragma unroll
    for (int i = 0; i < 8; ++i) {
      int kr = kb + (wv * 8 + i) * 2 + (lane >> 5);
      kr = kr < NACT ? kr : NACT - 1;  // dup row x g==0 pad -> 0 contribution
      const char* src = (const char*)w2 + ((size_t)kr * DIM + bx128) * 4 + (lane & 31) * 16;
      GLOAD16(src, db + i * 1024);
    }
  };
  auto GLOADG = [&](int c) {
    const bf16* p = pg + (size_t)c * 64;
#pragma unroll
    for (int m = 0; m < 2; ++m)
#pragma unroll
      for (int ks = 0; ks < 2; ++ks)
        gf[m][ks] = *(const bf16x8*)(p + (size_t)m * 16 * A_PAD + ks * 32);
  };
  auto COMP2 = [&](int b) {
    const char* base = &smem[b][0];
#pragma unroll
    for (int ks = 0; ks < 2; ++ks)
#pragma unroll
      for (int n = 0; n < 8; ++n) {
        bf16x8 wf;
#pragma unroll
        for (int j = 0; j < 8; ++j) {
          float f = *(const float*)(base + (ks * 32 + kh * 8 + j) * 512 + (n * 16 + ln) * 4);
          wf[j] = (bf16)f;
        }
#pragma unroll
        for (int m = 0; m < 2; ++m)
          acc[m][n] = __builtin_amdgcn_mfma_f32_16x16x32_bf16(gf[m][ks], wf, acc[m][n], 0, 0, 0);
      }
  };

  STAGE2(0, 0);
  for (int c = 0; c < NC2; ++c) {
    const int b = c & 1;
    GLOADG(c);         // outstanding: S(c)8 + g4
    WAITCNT(4);        // retire S(c); keep g
    BAR();
    if (c + 1 < NC2) {
      STAGE2(c + 1, b ^ 1);  // outstanding: g4 + S(c+1)8
      WAITCNT(8);            // retire g(c); keep S(c+1)
    } else {
      WAITCNT(0);
    }
    COMP2(b);
  }

  const int dbase = bx128 + ln;
#pragma unroll
  for (int m = 0; m < 2; ++m) {
#pragma unroll
    for (int n = 0; n < 8; ++n) {
#pragma unroll
      for (int j = 0; j < 4; ++j) {
        const int t = wv * 32 + m * 16 + kh * 4 + j;
        atomicAdd(out + (size_t)t * DIM + dbase + n * 16, acc[m][n][j]);
      }
    }
  }
}

// ---------------- launch ----------------
extern "C" void kernel_launch(void* const* d_in, const int* in_sizes, int n_in,
                              void* d_out, int out_size, void* d_ws, size_t ws_size,
                              hipStream_t stream) {
  const float* x    = (const float*)d_in[0];
  const float* ew   = (const float*)d_in[1];
  const int*   ids  = (const int*)d_in[2];
  const float* w1e0 = (const float*)d_in[3];
  const float* w3e0 = (const float*)d_in[4];
  const float* w2e0 = (const float*)d_in[5];
  const float* w1e1 = (const float*)d_in[6];
  const float* w3e1 = (const float*)d_in[7];
  const float* w2e1 = (const float*)d_in[8];
  float* out = (float*)d_out;

  bf16* xb = (bf16*)d_ws;                                   // 128*4096*2 = 1 MB (swizzled)
  bf16* g  = (bf16*)((char*)d_ws + (size_t)T * DIM * 2);    // 2 * 128*11520*2 = 5.9 MB

  hipMemsetAsync(d_out, 0, (size_t)T * DIM * sizeof(float), stream);
  k_cvt_x<<<dim3((T * DIM) / (256 * 8)), 256, 0, stream>>>(x, xb);
  k_phase1<<<dim3(A_PAD / 64, 2), 256, 0, stream>>>(xb, w1e0, w3e0, w1e1, w3e1, ew, ids, g);
  k_phase2<<<dim3(DIM / 128, 2 * NCH), 256, 0, stream>>>(g, w2e0, w2e1, out);
}